// Round 1
// baseline (756.028 us; speedup 1.0000x reference)
//
#include <hip/hip_runtime.h>

// 2-layer LSTM encoder, B=128, T=1024, F=1, HID=128, EMB=64.
// R10 = wave specialization:
//   - waves 4..7: ALL of layer-1 (8 gate-tiles each = 32 MFMAs, 32 h1 cells/wave,
//     depth-4 single accumulator chains, acc = 8 x f32x4)
//   - waves 0..3: ALL of layer-2 (4 gate-tiles x (4 ih + 2 hh) = 24 MFMAs,
//     2x depth-3 Lo/Hi chains as in R9)
//   - unified weight array WB[32] (128 VGPRs) shared by both roles so the
//     register allocator never sees L1+L2 weights co-live (was 160 in R9)
//   - removes the R4 intra-wave L1ew -> L2mfma serialization: the two layer
//     chains now overlap across waves; barrier arrival is balanced (32+2ew vs
//     24+1ew instead of 40+2ew vs 16+1ew)
//   - step 0 prologue needs no MFMA (h1(-1)=0 -> gates = x*w + b)
// Slot audit (unchanged from R8/R9): h1(m) -> H1[m&1]; h2(m) -> H2[m&1];
// epilogue reads h1(1023)=H1[1], h2(1022)=H2[0].

#define TB   1024
#define HID1 128
#define EMB2 64

typedef _Float16 f16x8 __attribute__((ext_vector_type(8)));
typedef float    f32x4 __attribute__((ext_vector_type(4)));

#define MFMA16(a,b,c) __builtin_amdgcn_mfma_f32_16x16x32_f16((a),(b),(c),0,0,0)

static __device__ __forceinline__ float fast_exp2(float x){
#if __has_builtin(__builtin_amdgcn_exp2f)
  return __builtin_amdgcn_exp2f(x);
#else
  return __exp2f(x);
#endif
}
static __device__ __forceinline__ float fast_rcp(float x){
#if __has_builtin(__builtin_amdgcn_rcpf)
  return __builtin_amdgcn_rcpf(x);
#else
  return 1.0f / x;
#endif
}
static __device__ __forceinline__ float sigmoid_f(float x){
  return fast_rcp(1.0f + fast_exp2(-1.44269504088896340736f * x));
}
static __device__ __forceinline__ float tanh_f(float x){
  return 1.0f - 2.0f * fast_rcp(1.0f + fast_exp2(2.88539008177792681472f * x));
}

static __device__ __forceinline__ f16x8 load_frag(const float* p){
  f16x8 r;
  #pragma unroll
  for (int j = 0; j < 8; ++j) r[j] = (_Float16)p[j];
  return r;
}

__launch_bounds__(512, 2)
__global__ void lstm2_kernel(const float* __restrict__ x,
                             const float* __restrict__ w_ih1,
                             const float* __restrict__ w_hh1,
                             const float* __restrict__ b_ih1,
                             const float* __restrict__ b_hh1,
                             const float* __restrict__ w_ih2,
                             const float* __restrict__ w_hh2,
                             const float* __restrict__ b_ih2,
                             const float* __restrict__ b_hh2,
                             float* __restrict__ out)
{
  __shared__ __align__(16) float    xs[TB];
  __shared__ __align__(16) _Float16 H1[2][HID1];  // h1 ping-pong
  __shared__ __align__(16) _Float16 H2[2][EMB2];  // h2 ping-pong

  const int t    = threadIdx.x;   // 0..511
  const int b    = blockIdx.x;    // 0..127
  const int l    = t & 63;        // lane
  const int w    = t >> 6;        // wave 0..7
  const int col  = l & 15;
  const int quad = l >> 4;
  const int role1 = w >> 2;       // 1 = layer-1 wave (4..7), 0 = layer-2 wave (0..3)
  const int idx   = w & 3;        // index within role

  // ---- unified weight fragments: one array, role-dependent contents ----
  // L1 wave idx: owns h1 cells [32*idx, 32*idx+32); gate g, half h -> tile
  //   n = 8*g + 2*idx + h; frag index fi = 2*g+h; WB[4*fi+k] = k-th K-chunk.
  // L2 wave idx: owns h2 cells [16*idx, 16*idx+16); gate g -> tile n = 4*g+idx;
  //   WB[4*g+k] = w_ih2 K-chunks (K=128), WB[16+2*g+k] = w_hh2 K-chunks (K=64).
  f16x8 WB[32];
  float bias[8], wx[8];

  if (role1){
    #pragma unroll
    for (int g = 0; g < 4; ++g){
      #pragma unroll
      for (int h = 0; h < 2; ++h){
        const int fi = 2*g + h;
        const int nc = (8*g + 2*idx + h)*16 + col;
        bias[fi] = b_ih1[nc] + b_hh1[nc];
        wx[fi]   = w_ih1[nc];                    // w_ih1 is (512,1)
        #pragma unroll
        for (int k = 0; k < 4; ++k)
          WB[4*fi + k] = load_frag(w_hh1 + nc*HID1 + k*32 + quad*8);
      }
    }
  } else {
    #pragma unroll
    for (int g = 0; g < 4; ++g){
      const int nc = (4*g + idx)*16 + col;
      bias[g]   = b_ih2[nc] + b_hh2[nc];
      bias[4+g] = 0.0f;
      wx[g]     = 0.0f;
      wx[4+g]   = 0.0f;
      #pragma unroll
      for (int k = 0; k < 4; ++k)
        WB[4*g + k] = load_frag(w_ih2 + nc*HID1 + k*32 + quad*8);
      #pragma unroll
      for (int k = 0; k < 2; ++k)
        WB[16 + 2*g + k] = load_frag(w_hh2 + nc*EMB2 + k*32 + quad*8);
    }
    #pragma unroll
    for (int k = 0; k < 8; ++k) WB[24 + k] = WB[k];   // keep array fully defined
  }

  // ---- x preload + state init ----
  xs[t]       = x[b * TB + t];
  xs[t + 512] = x[b * TB + t + 512];
  if (t < HID1) { H1[0][t] = (_Float16)0.0f; H1[1][t] = (_Float16)0.0f; }
  else if (t < HID1 + EMB2){
    H2[0][t-HID1] = (_Float16)0.0f; H2[1][t-HID1] = (_Float16)0.0f;
  }
  __syncthreads();

  float cA = 0.0f, cB = 0.0f;   // L1 wave: c1 of its two cell-groups; L2 wave: cA = c2
  const f32x4 zacc = {0.0f, 0.0f, 0.0f, 0.0f};

  // ---- prologue: L1 step 0. h1(-1)=0 so gates = x*w + b; no MFMA needed ----
  if (role1 && l < 16){
    const float xt = xs[0];
    #pragma unroll
    for (int h = 0; h < 2; ++h){
      float g4[4];
      #pragma unroll
      for (int g = 0; g < 4; ++g)
        g4[g] = __builtin_fmaf(xt, wx[2*g+h], bias[2*g+h]);
      float& c = h ? cB : cA;
      c = sigmoid_f(g4[1]) * c + sigmoid_f(g4[0]) * tanh_f(g4[2]);
      const float hv = sigmoid_f(g4[3]) * tanh_f(c);
      H1[0][32*idx + 16*h + l] = (_Float16)hv;
    }
  }
  __syncthreads();

  // ---- main pipelined loop: superstep s = L1(s) on waves 4-7 || L2(s-1) on
  //      waves 0-3, one barrier. Both roles read h1(s-1) = H1[(s+1)&1]. ----
  #pragma unroll 1
  for (int s = 1; s < TB; ++s){
    const int ra1 = (s + 1) & 1;       // h1(s-1) slot
    const int wa1 = s & 1;             // h1(s)   slot
    const int ra2 = s & 1;             // h2(s-2) slot
    const int wa2 = (s + 1) & 1;       // h2(s-1) slot

    const f16x8* pA1 = (const f16x8*)&H1[ra1][0];
    f16x8 a1[4];
    #pragma unroll
    for (int k = 0; k < 4; ++k) a1[k] = pA1[4*k + quad];

    if (role1){
      // ---- layer 1: 8 gate-tiles, depth-4 chains ----
      const float xt = xs[s];
      f32x4 acc[8];
      #pragma unroll
      for (int f = 0; f < 8; ++f) acc[f] = MFMA16(a1[0], WB[4*f], zacc);
      #pragma unroll
      for (int k = 1; k < 4; ++k){
        #pragma unroll
        for (int f = 0; f < 8; ++f) acc[f] = MFMA16(a1[k], WB[4*f + k], acc[f]);
      }
      if (l < 16){
        #pragma unroll
        for (int h = 0; h < 2; ++h){
          float g4[4];
          #pragma unroll
          for (int g = 0; g < 4; ++g)
            g4[g] = acc[2*g+h][0] + __builtin_fmaf(xt, wx[2*g+h], bias[2*g+h]);
          float& c = h ? cB : cA;
          c = sigmoid_f(g4[1]) * c + sigmoid_f(g4[0]) * tanh_f(g4[2]);
          const float hv = sigmoid_f(g4[3]) * tanh_f(c);
          H1[wa1][32*idx + 16*h + l] = (_Float16)hv;
        }
      }
    } else {
      // ---- layer 2: 4 gate-tiles, 2x depth-3 chains (ih k0,k1 + hh k0 |
      //      ih k2,k3 + hh k1) ----
      const f16x8* pA2 = (const f16x8*)&H2[ra2][0];
      f16x8 a2[2];
      #pragma unroll
      for (int k = 0; k < 2; ++k) a2[k] = pA2[4*k + quad];

      f32x4 lo[4], hi[4];
      #pragma unroll
      for (int g = 0; g < 4; ++g){
        lo[g] = MFMA16(a1[0], WB[4*g+0], zacc);
        hi[g] = MFMA16(a1[2], WB[4*g+2], zacc);
      }
      #pragma unroll
      for (int g = 0; g < 4; ++g){
        lo[g] = MFMA16(a1[1], WB[4*g+1], lo[g]);
        hi[g] = MFMA16(a1[3], WB[4*g+3], hi[g]);
      }
      #pragma unroll
      for (int g = 0; g < 4; ++g){
        lo[g] = MFMA16(a2[0], WB[16+2*g+0], lo[g]);
        hi[g] = MFMA16(a2[1], WB[16+2*g+1], hi[g]);
      }
      if (l < 16){
        float g4[4];
        #pragma unroll
        for (int g = 0; g < 4; ++g)
          g4[g] = lo[g][0] + hi[g][0] + bias[g];
        cA = sigmoid_f(g4[1]) * cA + sigmoid_f(g4[0]) * tanh_f(g4[2]);
        const float hv = sigmoid_f(g4[3]) * tanh_f(cA);
        H2[wa2][16*idx + l] = (_Float16)hv;
      }
    }
    __syncthreads();
  }

  // ---- epilogue: L2 step TB-1 -> output.
  //      h1(1023) in H1[1]; h2(1022) in H2[0] (slot = m&1) ----
  if (!role1){
    const f16x8* pA1 = (const f16x8*)&H1[1][0];
    f16x8 a1[4];
    #pragma unroll
    for (int k = 0; k < 4; ++k) a1[k] = pA1[4*k + quad];
    const f16x8* pA2 = (const f16x8*)&H2[0][0];
    f16x8 a2[2];
    #pragma unroll
    for (int k = 0; k < 2; ++k) a2[k] = pA2[4*k + quad];

    f32x4 lo[4], hi[4];
    #pragma unroll
    for (int g = 0; g < 4; ++g){
      lo[g] = MFMA16(a1[0], WB[4*g+0], zacc);
      hi[g] = MFMA16(a1[2], WB[4*g+2], zacc);
    }
    #pragma unroll
    for (int g = 0; g < 4; ++g){
      lo[g] = MFMA16(a1[1], WB[4*g+1], lo[g]);
      hi[g] = MFMA16(a1[3], WB[4*g+3], hi[g]);
    }
    #pragma unroll
    for (int g = 0; g < 4; ++g){
      lo[g] = MFMA16(a2[0], WB[16+2*g+0], lo[g]);
      hi[g] = MFMA16(a2[1], WB[16+2*g+1], hi[g]);
    }
    if (l < 16){
      float g4[4];
      #pragma unroll
      for (int g = 0; g < 4; ++g)
        g4[g] = lo[g][0] + hi[g][0] + bias[g];
      cA = sigmoid_f(g4[1]) * cA + sigmoid_f(g4[0]) * tanh_f(g4[2]);
      const float hv = sigmoid_f(g4[3]) * tanh_f(cA);
      out[b * EMB2 + 16*idx + l] = hv;
    }
  }
}

extern "C" void kernel_launch(void* const* d_in, const int* in_sizes, int n_in,
                              void* d_out, int out_size, void* d_ws, size_t ws_size,
                              hipStream_t stream) {
  lstm2_kernel<<<dim3(128), dim3(512), 0, stream>>>(
      (const float*)d_in[0],   // x
      (const float*)d_in[1],   // w_ih1
      (const float*)d_in[2],   // w_hh1
      (const float*)d_in[3],   // b_ih1
      (const float*)d_in[4],   // b_hh1
      (const float*)d_in[5],   // w_ih2
      (const float*)d_in[6],   // w_hh2
      (const float*)d_in[7],   // b_ih2
      (const float*)d_in[8],   // b_hh2
      (float*)d_out);
}